// Round 1
// baseline (358.321 us; speedup 1.0000x reference)
//
#include <hip/hip_runtime.h>
#include <stdint.h>

// Problem constants
#define M_TOK   16384        // 8 * 2048 tokens
#define EMBED   1024
#define FFN     4096
#define NQ      10

#define GK 4096
#define GN 1024
#define BK 32
#define NT (GK / BK)         // 128 K-tiles

typedef __attribute__((ext_vector_type(8))) short  bf16x8;
typedef __attribute__((ext_vector_type(4))) float  f32x4;
typedef __attribute__((ext_vector_type(8))) unsigned short u16x8;

static __device__ __forceinline__ unsigned short f2bf(float f) {
    union { float f; unsigned u; } v; v.f = f;
    unsigned r = v.u + 0x7FFF + ((v.u >> 16) & 1);   // round-to-nearest-even
    return (unsigned short)(r >> 16);
}

// ---------------------------------------------------------------------------
// Kernel 1: h[t][f] = relu( sum_i cos(x[t][i]) * cos(ry[i]) * w1[f][i] ) -> bf16
// grid (1024 token-tiles of 16, 2 f-tiles) = 2048 blocks (8/CU) for latency
// hiding; 256 threads, 8 f per thread. cq padded to stride 16.
// ---------------------------------------------------------------------------
__global__ __launch_bounds__(256) void compute_h(
    const float* __restrict__ x, const float* __restrict__ ry,
    const float* __restrict__ w1, unsigned short* __restrict__ h)
{
    __shared__ float cq[16 * 16];    // stride 16 for vector reads
    __shared__ float cry[NQ];

    const int tid = threadIdx.x;
    const int t0  = blockIdx.x * 16;
    const int fb  = blockIdx.y * 2048 + tid * 8;   // this thread's 8 f's

    if (tid < NQ) cry[tid] = cosf(ry[tid]);
    if (tid < 16 * NQ) {
        int t = tid / NQ;
        int i = tid - t * NQ;
        cq[t * 16 + i] = cosf(x[(size_t)(t0 + t) * EMBED + i]);
    }
    __syncthreads();

    // premultiply w1 rows by cos(phi): 80 floats in registers
    float wf[8][NQ];
#pragma unroll
    for (int fi = 0; fi < 8; ++fi)
#pragma unroll
        for (int i = 0; i < NQ; ++i)
            wf[fi][i] = w1[(fb + fi) * NQ + i] * cry[i];

    for (int t = 0; t < 16; ++t) {
        const float4 c0 = *(const float4*)&cq[t * 16 + 0];
        const float4 c1 = *(const float4*)&cq[t * 16 + 4];
        const float2 c2 = *(const float2*)&cq[t * 16 + 8];
        u16x8 v;
#pragma unroll
        for (int fi = 0; fi < 8; ++fi) {
            float s = c0.x * wf[fi][0] + c0.y * wf[fi][1] + c0.z * wf[fi][2]
                    + c0.w * wf[fi][3] + c1.x * wf[fi][4] + c1.y * wf[fi][5]
                    + c1.z * wf[fi][6] + c1.w * wf[fi][7] + c2.x * wf[fi][8]
                    + c2.y * wf[fi][9];
            v[fi] = f2bf(fmaxf(s, 0.f));
        }
        *(u16x8*)(h + (size_t)(t0 + t) * FFN + fb) = v;
    }
}

// ---------------------------------------------------------------------------
// Kernel 2: w2 fp32 -> bf16.  4,194,304 elems, 8 per thread.
// ---------------------------------------------------------------------------
__global__ __launch_bounds__(256) void conv_w2(
    const float* __restrict__ w2, unsigned short* __restrict__ o)
{
    const int idx = (blockIdx.x * 256 + threadIdx.x) * 8;
    float4 a = *(const float4*)(w2 + idx);
    float4 b = *(const float4*)(w2 + idx + 4);
    u16x8 v;
    v[0] = f2bf(a.x); v[1] = f2bf(a.y); v[2] = f2bf(a.z); v[3] = f2bf(a.w);
    v[4] = f2bf(b.x); v[5] = f2bf(b.y); v[6] = f2bf(b.z); v[7] = f2bf(b.w);
    *(u16x8*)(o + idx) = v;
}

// ---------------------------------------------------------------------------
// Kernel 3: C[M][N] = A[M][K] * B[N][K]^T   (bf16 in, fp32 out)
//
// Deep-pipelined phase schedule (T3+T4+T5):
//   256x256 tile, 512 threads = 8 waves (2M x 4N), per-wave 128x64 output.
//   BK=32, ring of 4 LDS buffers (4 x (16KB A + 16KB B) = 128 KB).
//   While computing K-tile T (buf T&3), stage K-tile T+2 (buf (T+2)&3):
//   provably race-free (that buf was last read at T-2, barrier-separated).
//   One counted s_waitcnt vmcnt(4) per K-tile retires exactly K(T+1)'s 4
//   loads, leaving K(T+2)'s 4 in flight -- never drains to 0 in the loop.
//   2 phases/K-tile, each: {ds_read subtile || 2x global_load_lds -> raw
//   s_barrier -> setprio(1) -> 16 MFMA -> setprio(0) -> s_barrier}.
//
//   LDS row = 32 bf16 = 64 B: adjacent rows are offset 16 banks, so the
//   16x16x32 fragment read (16 rows x 4 k-chunks of 16 B) spreads evenly
//   over all 32 banks -- conflict-free WITHOUT swizzle, which is required
//   since global_load_lds writes linearly (wave base + lane*16).
//
//   Staging map: thread -> tile row wv*32 + l*16 + (lane>>2), bytes
//   (lane&3)*16; LDS linear byte = wv*2048 + l*1024 + lane*16 = row*64+col.
//
//   Tail: T+2 >= NT stages k=0 garbage into never-read buffers to keep the
//   per-wave vmcnt count uniform (end-of-T=126 vmcnt(4) still retires K127).
//
//   Grid: 256 blocks (1/CU). XCD swizzle: xcd=bid&7 gets 32 contiguous wg;
//   n_blk = wg>>6 so each XCD works one 2 MB B-panel (L2-resident).
// ---------------------------------------------------------------------------
#define GL2LDS(g, l) \
    __builtin_amdgcn_global_load_lds( \
        (const __attribute__((address_space(1))) void*)(g), \
        (__attribute__((address_space(3))) void*)(l), 16, 0, 0)

__global__ __launch_bounds__(512, 2) void gemm_bt(
    const unsigned short* __restrict__ A,
    const unsigned short* __restrict__ B,
    float* __restrict__ C)
{
    __shared__ __align__(16) unsigned short As[4][256 * BK];   // 4 x 16 KB
    __shared__ __align__(16) unsigned short Bs[4][256 * BK];   // 4 x 16 KB

    const int tid  = threadIdx.x;
    const int wv   = tid >> 6;         // 0..7
    const int lane = tid & 63;
    const int wm   = wv >> 2;          // 0..1  (M half)
    const int wn   = wv & 3;           // 0..3  (N quarter)

    const int bid = blockIdx.x;
    const int wg  = (bid & 7) * 32 + (bid >> 3);   // XCD-chunked remap
    const int m0  = (wg & 63) * 256;               // 64 m-blocks
    const int n0  = (wg >> 6) * 256;               // 4 n-blocks

    // staging source pointers (element row = wv*32 + (lane>>2), +16 for l=1)
    const char* ag = (const char*)A +
        ((size_t)(m0 + wv * 32 + (lane >> 2)) * GK + (lane & 3) * 8) * 2;
    const char* bg = (const char*)B +
        ((size_t)(n0 + wv * 32 + (lane >> 2)) * GK + (lane & 3) * 8) * 2;
    const int ldsb = wv * 2048;        // this wave's staging byte offset

    // fragment read coordinates
    const int arow = wm * 128 + (lane & 15);
    const int brow = wn * 64  + (lane & 15);
    const int kch  = (lane >> 4) * 16;             // k-chunk byte offset

    f32x4 acc[8][4] = {};

    // prologue: stage K-tiles 0 and 1 (8 loads/thread), wait for K0
#pragma unroll
    for (int P = 0; P < 2; ++P) {
        GL2LDS(ag + P * (BK * 2),               (char*)As[P] + ldsb);
        GL2LDS(ag + P * (BK * 2) + 16 * GK * 2, (char*)As[P] + ldsb + 1024);
        GL2LDS(bg + P * (BK * 2),               (char*)Bs[P] + ldsb);
        GL2LDS(bg + P * (BK * 2) + 16 * GK * 2, (char*)Bs[P] + ldsb + 1024);
    }
    asm volatile("s_waitcnt vmcnt(4)" ::: "memory");
    __builtin_amdgcn_s_barrier();

#pragma unroll 1
    for (int T = 0; T < NT; ++T) {
        const char* At = (const char*)As[T & 3];
        const char* Bt = (const char*)Bs[T & 3];
        char* Ad = (char*)As[(T + 2) & 3] + ldsb;
        char* Bd = (char*)Bs[(T + 2) & 3] + ldsb;
        const size_t ks = (T + 2 < NT) ? (size_t)(T + 2) * (BK * 2) : 0;

        bf16x8 afr[4], bfr[4];

        // ---- phase 0: read B(all) + A(low), stage A(T+2), MFMA low half --
#pragma unroll
        for (int j = 0; j < 4; ++j)
            bfr[j] = *(const bf16x8*)(Bt + (brow + j * 16) * 64 + kch);
#pragma unroll
        for (int i = 0; i < 4; ++i)
            afr[i] = *(const bf16x8*)(At + (arow + i * 16) * 64 + kch);
        GL2LDS(ag + ks,               Ad);
        GL2LDS(ag + ks + 16 * GK * 2, Ad + 1024);
        __builtin_amdgcn_s_barrier();
        __builtin_amdgcn_s_setprio(1);
#pragma unroll
        for (int i = 0; i < 4; ++i)
#pragma unroll
            for (int j = 0; j < 4; ++j)
                acc[i][j] = __builtin_amdgcn_mfma_f32_16x16x32_bf16(
                    afr[i], bfr[j], acc[i][j], 0, 0, 0);
        __builtin_amdgcn_s_setprio(0);
        __builtin_amdgcn_s_barrier();

        // ---- phase 1: read A(high), stage B(T+2), MFMA high half ---------
#pragma unroll
        for (int i = 0; i < 4; ++i)
            afr[i] = *(const bf16x8*)(At + (arow + 64 + i * 16) * 64 + kch);
        GL2LDS(bg + ks,               Bd);
        GL2LDS(bg + ks + 16 * GK * 2, Bd + 1024);
        __builtin_amdgcn_s_barrier();
        __builtin_amdgcn_s_setprio(1);
#pragma unroll
        for (int i = 0; i < 4; ++i)
#pragma unroll
            for (int j = 0; j < 4; ++j)
                acc[4 + i][j] = __builtin_amdgcn_mfma_f32_16x16x32_bf16(
                    afr[i], bfr[j], acc[4 + i][j], 0, 0, 0);
        __builtin_amdgcn_s_setprio(0);
        // counted wait: retires exactly K(T+1)'s 4 loads; K(T+2)'s stay in flight
        asm volatile("s_waitcnt vmcnt(4)" ::: "memory");
        __builtin_amdgcn_s_barrier();
    }

    // epilogue: C/D layout col = lane&15, row = (lane>>4)*4 + reg
    const int cn = lane & 15;
    const int rb = (lane >> 4) * 4;
#pragma unroll
    for (int i = 0; i < 8; ++i)
#pragma unroll
        for (int j = 0; j < 4; ++j)
#pragma unroll
            for (int r = 0; r < 4; ++r) {
                const int m = m0 + wm * 128 + i * 16 + rb + r;
                const int n = n0 + wn * 64  + j * 16 + cn;
                C[(size_t)m * GN + n] = acc[i][j][r];
            }
}

// ---------------------------------------------------------------------------
extern "C" void kernel_launch(void* const* d_in, const int* in_sizes, int n_in,
                              void* d_out, int out_size, void* d_ws, size_t ws_size,
                              hipStream_t stream) {
    const float* x  = (const float*)d_in[0];
    const float* ry = (const float*)d_in[1];
    const float* w1 = (const float*)d_in[2];
    const float* w2 = (const float*)d_in[3];
    float* out = (float*)d_out;

    unsigned short* h   = (unsigned short*)d_ws;                       // 128 MiB
    unsigned short* w2b = (unsigned short*)((char*)d_ws +
                           (size_t)M_TOK * FFN * sizeof(unsigned short));

    compute_h<<<dim3(1024, 2), 256, 0, stream>>>(x, ry, w1, h);
    conv_w2<<<dim3((EMBED * FFN) / (256 * 8)), 256, 0, stream>>>(w2, w2b);
    gemm_bt<<<dim3(256), 512, 0, stream>>>(h, w2b, out);
}

// Round 2
// 284.260 us; speedup vs baseline: 1.2605x; 1.2605x over previous
//
#include <hip/hip_runtime.h>
#include <stdint.h>

// Problem constants
#define M_TOK   16384        // 8 * 2048 tokens
#define EMBED   1024
#define FFN     4096
#define NQ      10

#define GK 4096
#define GN 1024
#define BK 64
#define NT (GK / BK)         // 64 K-tiles

typedef __attribute__((ext_vector_type(8))) short  bf16x8;
typedef __attribute__((ext_vector_type(4))) float  f32x4;
typedef __attribute__((ext_vector_type(8))) unsigned short u16x8;
typedef __attribute__((ext_vector_type(4))) unsigned short u16x4;

static __device__ __forceinline__ unsigned short f2bf(float f) {
    union { float f; unsigned u; } v; v.f = f;
    unsigned r = v.u + 0x7FFF + ((v.u >> 16) & 1);   // round-to-nearest-even
    return (unsigned short)(r >> 16);
}

// ---------------------------------------------------------------------------
// Kernel 1: h[t][f] = relu( sum_i cos(x[t][i]) * cos(ry[i]) * w1[f][i] ) -> bf16
//
// Block = 32 tokens x 1024 f (4 f/thread). w1 slice (1024x10 = 40 KB) is
// staged to LDS ONCE per block with coalesced float4 loads (stride-11 rows
// to spread banks), killing the previous version's ~2.7 GB of uncoalesced
// per-thread w1 L2 traffic. Grid (512, 4) = 2048 blocks.
// ---------------------------------------------------------------------------
__global__ __launch_bounds__(256) void compute_h(
    const float* __restrict__ x, const float* __restrict__ ry,
    const float* __restrict__ w1, unsigned short* __restrict__ h)
{
    __shared__ float w1s[1024 * 11];     // 44 KB, stride 11
    __shared__ float cq[32 * 16];        // 2 KB
    __shared__ float cry[16];

    const int tid = threadIdx.x;
    const int t0  = blockIdx.x * 32;
    const int f0  = blockIdx.y * 1024;

    if (tid < NQ) cry[tid] = cosf(ry[tid]);
    for (int idx = tid; idx < 32 * NQ; idx += 256) {
        int t = idx / NQ;
        int i = idx - t * NQ;
        cq[t * 16 + i] = cosf(x[(size_t)(t0 + t) * EMBED + i]);
    }
    // stage w1 slice: 10240 contiguous floats, coalesced
    for (int idx = tid; idx < (1024 * NQ) / 4; idx += 256) {
        float4 v = *(const float4*)(w1 + (size_t)f0 * NQ + idx * 4);
        int e = idx * 4;
#pragma unroll
        for (int k = 0; k < 4; ++k) {
            int ee = e + k;
            int r  = ee / NQ;
            int c  = ee - r * NQ;
            w1s[r * 11 + c] = ((const float*)&v)[k];
        }
    }
    __syncthreads();

    // premultiply w1 rows by cos(phi): 40 floats in registers (one-time LDS read)
    float wf[4][NQ];
#pragma unroll
    for (int fi = 0; fi < 4; ++fi)
#pragma unroll
        for (int i = 0; i < NQ; ++i)
            wf[fi][i] = w1s[(tid * 4 + fi) * 11 + i] * cry[i];

    for (int t = 0; t < 32; ++t) {
        const float4 c0 = *(const float4*)&cq[t * 16 + 0];
        const float4 c1 = *(const float4*)&cq[t * 16 + 4];
        const float2 c2 = *(const float2*)&cq[t * 16 + 8];
        u16x4 v;
#pragma unroll
        for (int fi = 0; fi < 4; ++fi) {
            float s = c0.x * wf[fi][0] + c0.y * wf[fi][1] + c0.z * wf[fi][2]
                    + c0.w * wf[fi][3] + c1.x * wf[fi][4] + c1.y * wf[fi][5]
                    + c1.z * wf[fi][6] + c1.w * wf[fi][7] + c2.x * wf[fi][8]
                    + c2.y * wf[fi][9];
            v[fi] = f2bf(fmaxf(s, 0.f));
        }
        *(u16x4*)(h + (size_t)(t0 + t) * FFN + f0 + tid * 4) = v;
    }
}

// ---------------------------------------------------------------------------
// Kernel 2: w2 fp32 -> bf16.  4,194,304 elems, 8 per thread.
// ---------------------------------------------------------------------------
__global__ __launch_bounds__(256) void conv_w2(
    const float* __restrict__ w2, unsigned short* __restrict__ o)
{
    const int idx = (blockIdx.x * 256 + threadIdx.x) * 8;
    float4 a = *(const float4*)(w2 + idx);
    float4 b = *(const float4*)(w2 + idx + 4);
    u16x8 v;
    v[0] = f2bf(a.x); v[1] = f2bf(a.y); v[2] = f2bf(a.z); v[3] = f2bf(a.w);
    v[4] = f2bf(b.x); v[5] = f2bf(b.y); v[6] = f2bf(b.z); v[7] = f2bf(b.w);
    *(u16x8*)(o + idx) = v;
}

// ---------------------------------------------------------------------------
// Kernel 3: C[M][N] = A[M][K] * B[N][K]^T   (bf16 in, fp32 out)
//
// 256x256 tile, 512 threads = 8 waves (2M x 4N), per-wave 128x64 output.
// BK=64: LDS row = 128 B (full L2 line per row per tile -> no granularity
// over-fetch) with the PROVEN conflict-free XOR chunk swizzle:
//   staging lane -> row lane>>3, global chunk (lane&7)^(lane>>3); image
//   LDS[r][c] = global[r][c ^ (r&7)]; fragment read slot (s*4+cc)^(lane&7).
//
// Ring-2 pipeline: all 8 staging loads for tile T+1 are issued at the START
// of tile T (before ds_reads); the vmcnt(0) at tile end therefore retires
// loads issued ~2480 MFMA-cycles earlier -> latency fully hidden without a
// deep ring. ONE barrier per K-tile (64 total vs 512 in the failed version):
// buffers are stable for the whole tile, and the end-of-tile
// vmcnt(0)+s_barrier establishes both "tile T+1 fully staged" and "all
// waves done reading buf[T&1]" before anyone overwrites it.
//
// Grid: 256 blocks (1/CU). wg = (bid&7)*32 + bid>>3: each XCD gets 32
// contiguous wg = 8 m-panels x 4 n -> A-panel shared within one XCD's L2.
// ---------------------------------------------------------------------------
#define GL2LDS(g, l) \
    __builtin_amdgcn_global_load_lds( \
        (const __attribute__((address_space(1))) void*)(g), \
        (__attribute__((address_space(3))) void*)(l), 16, 0, 0)

__global__ __launch_bounds__(512, 2) void gemm_bt(
    const unsigned short* __restrict__ A,
    const unsigned short* __restrict__ B,
    float* __restrict__ C)
{
    __shared__ __align__(16) unsigned short As[2][256 * BK];   // 2 x 32 KB
    __shared__ __align__(16) unsigned short Bs[2][256 * BK];   // 2 x 32 KB

    const int tid  = threadIdx.x;
    const int wv   = tid >> 6;         // 0..7
    const int lane = tid & 63;
    const int wm   = wv >> 2;          // 0..1  (M half)
    const int wn   = wv & 3;           // 0..3  (N quarter)

    const int bid = blockIdx.x;
    const int wg  = (bid & 7) * 32 + (bid >> 3);   // XCD-chunked remap
    const int m0  = (wg >> 2) * 256;               // 64 m-blocks
    const int n0  = (wg & 3) * 256;                // 4 n-blocks

    // staging: lane -> row lane>>3 within 8-row group, chunk (lane&7)^row
    const int srow = lane >> 3;
    const int schk = (lane & 7) ^ srow;
    const char* ag = (const char*)A +
        ((size_t)(m0 + wv * 32 + srow) * GK + schk * 8) * 2;
    const char* bg = (const char*)B +
        ((size_t)(n0 + wv * 32 + srow) * GK + schk * 8) * 2;
    const int ldsb = (wv * 32) * 128;  // this wave's staging byte base

    // fragment read coordinates
    const int rr  = lane & 15;
    const int fsw = lane & 7;          // row&7 for swizzle
    const int cc  = lane >> 4;         // 0..3

    f32x4 acc[8][4] = {};

    // prologue: stage tile 0 into buf 0
#pragma unroll
    for (int l = 0; l < 4; ++l) {
        GL2LDS(ag + (size_t)l * 8 * (GK * 2), (char*)As[0] + ldsb + l * 1024);
        GL2LDS(bg + (size_t)l * 8 * (GK * 2), (char*)Bs[0] + ldsb + l * 1024);
    }
    asm volatile("s_waitcnt vmcnt(0)" ::: "memory");
    __builtin_amdgcn_s_barrier();

#pragma unroll 1
    for (int T = 0; T < NT; ++T) {
        const char* At = (const char*)As[T & 1];
        const char* Bt = (const char*)Bs[T & 1];

        // issue ALL of tile T+1's staging loads up front (max latency cover)
        if (T + 1 < NT) {
            char* Ad = (char*)As[(T + 1) & 1] + ldsb;
            char* Bd = (char*)Bs[(T + 1) & 1] + ldsb;
            const size_t ko = (size_t)(T + 1) * 128;   // byte offset along row
#pragma unroll
            for (int l = 0; l < 4; ++l) {
                GL2LDS(ag + ko + (size_t)l * 8 * (GK * 2), Ad + l * 1024);
                GL2LDS(bg + ko + (size_t)l * 8 * (GK * 2), Bd + l * 1024);
            }
        }

#pragma unroll
        for (int s = 0; s < 2; ++s) {
            const int choff = ((s * 4 + cc) ^ fsw) * 16;
            bf16x8 bfr[4], afr[4];
#pragma unroll
            for (int j = 0; j < 4; ++j)
                bfr[j] = *(const bf16x8*)(Bt + (wn * 64 + j * 16 + rr) * 128 + choff);
#pragma unroll
            for (int i = 0; i < 4; ++i)
                afr[i] = *(const bf16x8*)(At + (wm * 128 + i * 16 + rr) * 128 + choff);
            __builtin_amdgcn_s_setprio(1);
#pragma unroll
            for (int i = 0; i < 4; ++i)
#pragma unroll
                for (int j = 0; j < 4; ++j)
                    acc[i][j] = __builtin_amdgcn_mfma_f32_16x16x32_bf16(
                        afr[i], bfr[j], acc[i][j], 0, 0, 0);
            __builtin_amdgcn_s_setprio(0);
#pragma unroll
            for (int i = 0; i < 4; ++i)
                afr[i] = *(const bf16x8*)(At + (wm * 128 + 64 + i * 16 + rr) * 128 + choff);
            __builtin_amdgcn_s_setprio(1);
#pragma unroll
            for (int i = 0; i < 4; ++i)
#pragma unroll
                for (int j = 0; j < 4; ++j)
                    acc[4 + i][j] = __builtin_amdgcn_mfma_f32_16x16x32_bf16(
                        afr[i], bfr[j], acc[4 + i][j], 0, 0, 0);
            __builtin_amdgcn_s_setprio(0);
        }

        // tile T+1 staged (my loads done; barrier makes it all-waves) and
        // everyone is done reading buf[T&1] -> safe to overwrite next tile
        asm volatile("s_waitcnt vmcnt(0)" ::: "memory");
        __builtin_amdgcn_s_barrier();
    }

    // epilogue: C/D layout col = lane&15, row = (lane>>4)*4 + reg
    const int cn = lane & 15;
    const int rb = (lane >> 4) * 4;
#pragma unroll
    for (int i = 0; i < 8; ++i)
#pragma unroll
        for (int j = 0; j < 4; ++j)
#pragma unroll
            for (int r = 0; r < 4; ++r) {
                const int m = m0 + wm * 128 + i * 16 + rb + r;
                const int n = n0 + wn * 64 + j * 16 + cn;
                C[(size_t)m * GN + n] = acc[i][j][r];
            }
}

// ---------------------------------------------------------------------------
extern "C" void kernel_launch(void* const* d_in, const int* in_sizes, int n_in,
                              void* d_out, int out_size, void* d_ws, size_t ws_size,
                              hipStream_t stream) {
    const float* x  = (const float*)d_in[0];
    const float* ry = (const float*)d_in[1];
    const float* w1 = (const float*)d_in[2];
    const float* w2 = (const float*)d_in[3];
    float* out = (float*)d_out;

    unsigned short* h   = (unsigned short*)d_ws;                       // 128 MiB
    unsigned short* w2b = (unsigned short*)((char*)d_ws +
                           (size_t)M_TOK * FFN * sizeof(unsigned short));

    compute_h<<<dim3(512, 4), 256, 0, stream>>>(x, ry, w1, h);
    conv_w2<<<dim3((EMBED * FFN) / (256 * 8)), 256, 0, stream>>>(w2, w2b);
    gemm_bt<<<dim3(256), 512, 0, stream>>>(h, w2b, out);
}

// Round 3
// 266.323 us; speedup vs baseline: 1.3454x; 1.0674x over previous
//
#include <hip/hip_runtime.h>
#include <stdint.h>

// Problem constants
#define M_TOK   16384        // 8 * 2048 tokens
#define EMBED   1024
#define FFN     4096
#define NQ      10

#define GK 4096
#define GN 1024
#define BK 64
#define NT (GK / BK)         // 64 K-tiles

typedef __attribute__((ext_vector_type(8))) short  bf16x8;
typedef __attribute__((ext_vector_type(4))) float  f32x4;
typedef __attribute__((ext_vector_type(8))) unsigned short u16x8;

static __device__ __forceinline__ unsigned short f2bf(float f) {
    union { float f; unsigned u; } v; v.f = f;
    unsigned r = v.u + 0x7FFF + ((v.u >> 16) & 1);   // round-to-nearest-even
    return (unsigned short)(r >> 16);
}

// ---------------------------------------------------------------------------
// Kernel 1: h[t][f] = relu( sum_i cos(x[t][i]) * cos(ry[i]) * w1[f][i] ) -> bf16
// Round-0 version (empirically best "rest" time): 32 tokens x 2048 f per
// block, 8 f/thread, w1 read direct from global (L2-cached).
// ---------------------------------------------------------------------------
__global__ __launch_bounds__(256) void compute_h(
    const float* __restrict__ x, const float* __restrict__ ry,
    const float* __restrict__ w1, unsigned short* __restrict__ h)
{
    __shared__ float cq[32 * 16];    // 2 KB, stride 16 for alignment
    __shared__ float cry[NQ];

    const int tid = threadIdx.x;
    const int t0  = blockIdx.x * 32;
    const int fb  = blockIdx.y * 2048 + tid * 8;   // this thread's 8 f's

    if (tid < NQ) cry[tid] = cosf(ry[tid]);
    for (int idx = tid; idx < 32 * NQ; idx += 256) {
        int t = idx / NQ;
        int i = idx - t * NQ;
        cq[t * 16 + i] = cosf(x[(size_t)(t0 + t) * EMBED + i]);
    }
    __syncthreads();

    // premultiply w1 rows by cos(phi): 80 floats in registers
    float wf[8][NQ];
#pragma unroll
    for (int fi = 0; fi < 8; ++fi)
#pragma unroll
        for (int i = 0; i < NQ; ++i)
            wf[fi][i] = w1[(fb + fi) * NQ + i] * cry[i];

    for (int t = 0; t < 32; ++t) {
        const float4 c0 = *(const float4*)&cq[t * 16 + 0];
        const float4 c1 = *(const float4*)&cq[t * 16 + 4];
        const float2 c2 = *(const float2*)&cq[t * 16 + 8];
        u16x8 v;
#pragma unroll
        for (int fi = 0; fi < 8; ++fi) {
            float s = c0.x * wf[fi][0] + c0.y * wf[fi][1] + c0.z * wf[fi][2]
                    + c0.w * wf[fi][3] + c1.x * wf[fi][4] + c1.y * wf[fi][5]
                    + c1.z * wf[fi][6] + c1.w * wf[fi][7] + c2.x * wf[fi][8]
                    + c2.y * wf[fi][9];
            v[fi] = f2bf(fmaxf(s, 0.f));
        }
        *(u16x8*)(h + (size_t)(t0 + t) * FFN + fb) = v;
    }
}

// ---------------------------------------------------------------------------
// Kernel 2: w2 fp32 -> bf16.  4,194,304 elems, 8 per thread.
// ---------------------------------------------------------------------------
__global__ __launch_bounds__(256) void conv_w2(
    const float* __restrict__ w2, unsigned short* __restrict__ o)
{
    const int idx = (blockIdx.x * 256 + threadIdx.x) * 8;
    float4 a = *(const float4*)(w2 + idx);
    float4 b = *(const float4*)(w2 + idx + 4);
    u16x8 v;
    v[0] = f2bf(a.x); v[1] = f2bf(a.y); v[2] = f2bf(a.z); v[3] = f2bf(a.w);
    v[4] = f2bf(b.x); v[5] = f2bf(b.y); v[6] = f2bf(b.z); v[7] = f2bf(b.w);
    *(u16x8*)(o + idx) = v;
}

// ---------------------------------------------------------------------------
// Kernel 3: C[M][N] = A[M][K] * B[N][K]^T   (bf16 in, fp32 out)
//
// 4-phase-per-K-tile schedule (T3+T5 on top of the verified R2 kernel).
// 256x256 tile, 512 threads = 8 waves (2M x 4N), per-wave 128x64 output.
// BK=64, 128 B LDS rows with the verified XOR chunk swizzle (0 conflicts).
//
// Per K-tile T (buf c = T&1), each phase = one C-quadrant x K=64:
//   P1 Q(mh0,nh0): ds_read A-mh0(8) + B-nh0(4) | stage A(T+1) both halves
//   P2 Q(mh0,nh1): ds_read B-nh1(4)            | stage B(T+1) both halves
//   P3 Q(mh1,nh1): ds_read A-mh1(8)
//   P4 Q(mh1,nh0): no reads (A-mh1, B-nh0 held in regs)
// each phase: reads/stage -> s_barrier -> lgkmcnt(0) -> setprio(1) ->
// 16 MFMA -> setprio(0) -> s_barrier. The phase split lets waves time-share
// the LDS pipe (~2300 cyc/tile) under the MFMA pipe (~2480 cyc/tile) instead
// of lockstep-serializing; setprio keeps MFMA-phase waves fed.
//
// vmcnt(0) at tile end retires loads issued >= 2 phases (>=1240 cyc) earlier
// (HBM latency ~900) -> expected-free, counted-equivalent. Each wave reads
// only A-half(wm) / B-half(wn>>1); publication = every wave's vmcnt before
// the P4 barrier. Buf c is overwritten at T+1.P1, two barriers after the
// last buf-c ds_read completes (P3's lgkmcnt + trailing barrier).
//
// Registers: acc 128 + A-frags 32 + B-nh0 16 + B-nh1 16 ~= 192 + addr.
// ---------------------------------------------------------------------------
#define GL2LDS(g, l) \
    __builtin_amdgcn_global_load_lds( \
        (const __attribute__((address_space(1))) void*)(g), \
        (__attribute__((address_space(3))) void*)(l), 16, 0, 0)

__global__ __launch_bounds__(512, 2) void gemm_bt(
    const unsigned short* __restrict__ A,
    const unsigned short* __restrict__ B,
    float* __restrict__ C)
{
    __shared__ __align__(16) unsigned short As[2][256 * BK];   // 2 x 32 KB
    __shared__ __align__(16) unsigned short Bs[2][256 * BK];   // 2 x 32 KB

    const int tid  = threadIdx.x;
    const int wv   = tid >> 6;         // 0..7
    const int lane = tid & 63;
    const int wm   = wv >> 2;          // 0..1  (M half)
    const int wn   = wv & 3;           // 0..3  (N quarter)

    const int bid = blockIdx.x;
    const int wg  = (bid & 7) * 32 + (bid >> 3);   // XCD-chunked remap
    const int m0  = (wg >> 2) * 256;               // 64 m-blocks
    const int n0  = (wg & 3) * 256;                // 4 n-blocks

    // staging: per half-tile (128 rows), wave wv covers 16 rows as 2 loads of
    // 8 rows; lane -> row lane>>3, chunk (lane&7)^(lane>>3) (XOR swizzle).
    const int srow8 = lane >> 3;
    const int schk  = (lane & 7) ^ srow8;
    const char* ag = (const char*)A +
        ((size_t)(m0 + wv * 16 + srow8) * GK + schk * 8) * 2;
    const char* bg = (const char*)B +
        ((size_t)(n0 + wv * 16 + srow8) * GK + schk * 8) * 2;
    const size_t ROW8 = (size_t)8 * GK * 2;     // 8 rows in global bytes
    const size_t HALF = (size_t)128 * GK * 2;   // 128 rows in global bytes

#define STAGE_A(buf, half, ko) do { \
    GL2LDS(ag + (ko) + (half) * HALF,        (char*)As[buf] + ((half) * 128 + wv * 16) * 128); \
    GL2LDS(ag + (ko) + (half) * HALF + ROW8, (char*)As[buf] + ((half) * 128 + wv * 16 + 8) * 128); \
} while (0)
#define STAGE_B(buf, half, ko) do { \
    GL2LDS(bg + (ko) + (half) * HALF,        (char*)Bs[buf] + ((half) * 128 + wv * 16) * 128); \
    GL2LDS(bg + (ko) + (half) * HALF + ROW8, (char*)Bs[buf] + ((half) * 128 + wv * 16 + 8) * 128); \
} while (0)

    // fragment read coordinates (verified layout from R2 kernel)
    const int rr  = lane & 15;
    const int fsw = lane & 7;
    const int cc  = lane >> 4;
#define CHOFF(s) ((((s) * 4 + cc) ^ fsw) * 16)
#define AFRAG(mh, i, s) (*(const bf16x8*)(At + (wm * 128 + (mh) * 64 + (i) * 16 + rr) * 128 + CHOFF(s)))
#define BFRAG(nh, j, s) (*(const bf16x8*)(Bt + (wn * 64 + (nh) * 32 + (j) * 16 + rr) * 128 + CHOFF(s)))

    f32x4 acc[8][4] = {};

    // prologue: stage tile 0 (all four halves), drain, publish
    STAGE_A(0, 0, 0); STAGE_A(0, 1, 0);
    STAGE_B(0, 0, 0); STAGE_B(0, 1, 0);
    asm volatile("s_waitcnt vmcnt(0)" ::: "memory");
    __builtin_amdgcn_s_barrier();

#pragma unroll 1
    for (int T = 0; T < NT; ++T) {
        const char* At = (const char*)As[T & 1];
        const char* Bt = (const char*)Bs[T & 1];
        const int nb   = (T + 1) & 1;
        const size_t ko = (size_t)(T + 1) * 128;   // K byte offset of tile T+1
        const bool st  = (T + 1 < NT);

        bf16x8 afr[2][4];   // current A half fragments [s][i]
        bf16x8 b0r[2][2];   // B nh0 [s][j]
        bf16x8 b1r[2][2];   // B nh1 [s][j]

        // ---- P1: Q(mh0, nh0) ------------------------------------------
#pragma unroll
        for (int s = 0; s < 2; ++s) {
#pragma unroll
            for (int i = 0; i < 4; ++i) afr[s][i] = AFRAG(0, i, s);
#pragma unroll
            for (int j = 0; j < 2; ++j) b0r[s][j] = BFRAG(0, j, s);
        }
        if (st) { STAGE_A(nb, 0, ko); STAGE_A(nb, 1, ko); }
        __builtin_amdgcn_s_barrier();
        asm volatile("s_waitcnt lgkmcnt(0)" ::: "memory");
        __builtin_amdgcn_sched_barrier(0);
        __builtin_amdgcn_s_setprio(1);
#pragma unroll
        for (int s = 0; s < 2; ++s)
#pragma unroll
            for (int i = 0; i < 4; ++i)
#pragma unroll
                for (int j = 0; j < 2; ++j)
                    acc[i][j] = __builtin_amdgcn_mfma_f32_16x16x32_bf16(
                        afr[s][i], b0r[s][j], acc[i][j], 0, 0, 0);
        __builtin_amdgcn_s_setprio(0);
        __builtin_amdgcn_s_barrier();

        // ---- P2: Q(mh0, nh1) ------------------------------------------
#pragma unroll
        for (int s = 0; s < 2; ++s)
#pragma unroll
            for (int j = 0; j < 2; ++j) b1r[s][j] = BFRAG(1, j, s);
        if (st) { STAGE_B(nb, 0, ko); STAGE_B(nb, 1, ko); }
        __builtin_amdgcn_s_barrier();
        asm volatile("s_waitcnt lgkmcnt(0)" ::: "memory");
        __builtin_amdgcn_sched_barrier(0);
        __builtin_amdgcn_s_setprio(1);
#pragma unroll
        for (int s = 0; s < 2; ++s)
#pragma unroll
            for (int i = 0; i < 4; ++i)
#pragma unroll
                for (int j = 0; j < 2; ++j)
                    acc[i][2 + j] = __builtin_amdgcn_mfma_f32_16x16x32_bf16(
                        afr[s][i], b1r[s][j], acc[i][2 + j], 0, 0, 0);
        __builtin_amdgcn_s_setprio(0);
        __builtin_amdgcn_s_barrier();

        // ---- P3: Q(mh1, nh1) ------------------------------------------
#pragma unroll
        for (int s = 0; s < 2; ++s)
#pragma unroll
            for (int i = 0; i < 4; ++i) afr[s][i] = AFRAG(1, i, s);
        __builtin_amdgcn_s_barrier();
        asm volatile("s_waitcnt lgkmcnt(0)" ::: "memory");
        __builtin_amdgcn_sched_barrier(0);
        __builtin_amdgcn_s_setprio(1);
#pragma unroll
        for (int s = 0; s < 2; ++s)
#pragma unroll
            for (int i = 0; i < 4; ++i)
#pragma unroll
                for (int j = 0; j < 2; ++j)
                    acc[4 + i][2 + j] = __builtin_amdgcn_mfma_f32_16x16x32_bf16(
                        afr[s][i], b1r[s][j], acc[4 + i][2 + j], 0, 0, 0);
        __builtin_amdgcn_s_setprio(0);
        __builtin_amdgcn_s_barrier();

        // ---- P4: Q(mh1, nh0) -- no new reads --------------------------
        __builtin_amdgcn_s_setprio(1);
#pragma unroll
        for (int s = 0; s < 2; ++s)
#pragma unroll
            for (int i = 0; i < 4; ++i)
#pragma unroll
                for (int j = 0; j < 2; ++j)
                    acc[4 + i][j] = __builtin_amdgcn_mfma_f32_16x16x32_bf16(
                        afr[s][i], b0r[s][j], acc[4 + i][j], 0, 0, 0);
        __builtin_amdgcn_s_setprio(0);
        // retire T+1's stages (issued >=2 phases ago -> expected-free) and
        // publish: next iteration may read buf nb and overwrite buf c.
        asm volatile("s_waitcnt vmcnt(0)" ::: "memory");
        __builtin_amdgcn_s_barrier();
    }

    // epilogue: C/D layout col = lane&15, row = (lane>>4)*4 + reg
    const int cn = lane & 15;
    const int rb = (lane >> 4) * 4;
#pragma unroll
    for (int i = 0; i < 8; ++i)
#pragma unroll
        for (int j = 0; j < 4; ++j)
#pragma unroll
            for (int r = 0; r < 4; ++r) {
                const int m = m0 + wm * 128 + i * 16 + rb + r;
                const int n = n0 + wn * 64 + j * 16 + cn;
                C[(size_t)m * GN + n] = acc[i][j][r];
            }
}

// ---------------------------------------------------------------------------
extern "C" void kernel_launch(void* const* d_in, const int* in_sizes, int n_in,
                              void* d_out, int out_size, void* d_ws, size_t ws_size,
                              hipStream_t stream) {
    const float* x  = (const float*)d_in[0];
    const float* ry = (const float*)d_in[1];
    const float* w1 = (const float*)d_in[2];
    const float* w2 = (const float*)d_in[3];
    float* out = (float*)d_out;

    unsigned short* h   = (unsigned short*)d_ws;                       // 128 MiB
    unsigned short* w2b = (unsigned short*)((char*)d_ws +
                           (size_t)M_TOK * FFN * sizeof(unsigned short));

    compute_h<<<dim3(512, 2), 256, 0, stream>>>(x, ry, w1, h);
    conv_w2<<<dim3((EMBED * FFN) / (256 * 8)), 256, 0, stream>>>(w2, w2b);
    gemm_bt<<<dim3(256), 512, 0, stream>>>(h, w2b, out);
}